// Round 4
// baseline (10861.774 us; speedup 1.0000x reference)
//
#include <hip/hip_runtime.h>
#include <hip/hip_bf16.h>
#include <math.h>

// SimpleRNN: B=64, T=512, IN=512, UNITS=512, fp32.
// Phase 1: xw = x @ W_in + b -> d_out[b][t][u] (in-place reuse).
// Phase 2: cooperative scan, 256 blocks = 32 groups x 8 blocks.
//   group g owns batches {2g,2g+1}; block j owns columns [64j,64j+64).
//   W_rec[:,u0:u0+64] (128 KB fp32) resident in LDS.
//   Per step: each wave waits ONLY on its 2 source peers' flags (relaxed poll +
//   acquire fence), loads its h chunk, computes a 128-k partial dot, ONE
//   __syncthreads (double-buffered partials), reducer waves do
//   reduce+tanh+store h+release-flag. No atomic RMW, no threadfence, no sleep.
// NOTE: tanhf (exact) kept deliberately — numerics identical to the round-1
// pass (absmax 0.0039); fast exp2-based tanh is a later A/B.

#define B_ 64
#define T_ 512
#define U_ 512

// ---------------- Kernel A: xw = x @ W_in + bias ----------------
__global__ __launch_bounds__(256)
void rnn_inproj_gemm(const float* __restrict__ X, const float* __restrict__ Win,
                     const float* __restrict__ bias, float* __restrict__ out) {
    __shared__ float As[16][128];  // [k][m]
    __shared__ float Bs[16][128];  // [k][n]

    const int m0 = blockIdx.x * 128;
    const int n0 = blockIdx.y * 128;
    const int tid = threadIdx.x;
    const int tx = tid & 15;
    const int ty = tid >> 4;

    float acc[8][8];
#pragma unroll
    for (int i = 0; i < 8; ++i)
#pragma unroll
        for (int j = 0; j < 8; ++j) acc[i][j] = 0.f;

    for (int k0 = 0; k0 < 512; k0 += 16) {
#pragma unroll
        for (int i = 0; i < 2; ++i) {
            int li = tid * 2 + i;
            int row = li >> 2;
            int c4 = li & 3;
            float4 v = *(const float4*)&X[(size_t)(m0 + row) * 512 + k0 + c4 * 4];
            As[c4 * 4 + 0][row] = v.x;
            As[c4 * 4 + 1][row] = v.y;
            As[c4 * 4 + 2][row] = v.z;
            As[c4 * 4 + 3][row] = v.w;
        }
#pragma unroll
        for (int i = 0; i < 2; ++i) {
            int li = tid * 2 + i;
            int row = li >> 5;
            int c4 = li & 31;
            float4 v = *(const float4*)&Win[(size_t)(k0 + row) * 512 + n0 + c4 * 4];
            *(float4*)&Bs[row][c4 * 4] = v;
        }
        __syncthreads();

#pragma unroll
        for (int k = 0; k < 16; ++k) {
            float a[8], b[8];
            *(float4*)&a[0] = *(float4*)&As[k][ty * 8];
            *(float4*)&a[4] = *(float4*)&As[k][ty * 8 + 4];
            *(float4*)&b[0] = *(float4*)&Bs[k][tx * 8];
            *(float4*)&b[4] = *(float4*)&Bs[k][tx * 8 + 4];
#pragma unroll
            for (int i = 0; i < 8; ++i)
#pragma unroll
                for (int j = 0; j < 8; ++j) acc[i][j] += a[i] * b[j];
        }
        __syncthreads();
    }

#pragma unroll
    for (int i = 0; i < 8; ++i) {
        int m = m0 + ty * 8 + i;
#pragma unroll
        for (int j = 0; j < 8; j += 4) {
            int n = n0 + tx * 8 + j;
            float4 bv = *(const float4*)&bias[n];
            float4 o;
            o.x = acc[i][j + 0] + bv.x;
            o.y = acc[i][j + 1] + bv.y;
            o.z = acc[i][j + 2] + bv.z;
            o.w = acc[i][j + 3] + bv.w;
            *(float4*)&out[(size_t)m * 512 + n] = o;
        }
    }
}

// ---------------- Kernel B: the recurrent scan ----------------

__device__ __forceinline__ float lane_bcast(float v, int l) {
    return __int_as_float(__builtin_amdgcn_readlane(__float_as_int(v), l));
}

__global__ __launch_bounds__(512, 1)
void rnn_scan(const float* __restrict__ Wrec, float* __restrict__ out,
              unsigned* __restrict__ flags) {
    __shared__ float Wl[512][64];        // 128 KB: W_rec[:, u0:u0+64]
    __shared__ float part[2][4][2][64];  // 4 KB: double-buffered partials [buf][ks][b][u]

    const int bid = blockIdx.x;
    // Keep all 8 blocks of a group on the same blockIdx%8 residue (same XCD
    // under round-robin) for L2-local flag/h traffic. Correctness is
    // placement-independent (agent-scope protocol).
    const int xcd = bid & 7;
    const int r = bid >> 3;
    const int slot = r >> 3;       // 0..3
    const int j = r & 7;           // column-slice index within group
    const int g = xcd + 8 * slot;  // group 0..31

    const int u0 = j * 64;
    const int tid = threadIdx.x;
    const int lane = tid & 63;
    const int w = tid >> 6;        // wave 0..7
    const int ks = w >> 1;         // k-split 0..3 (128 k's each)
    const int b = w & 1;           // batch-half within group
    const int bb = 2 * g + b;

    // Load W_rec column slice into LDS (once).
    for (int i = tid; i < 512 * 16; i += 512) {
        int k = i >> 4;
        int c4 = i & 15;
        float4 v = *(const float4*)&Wrec[(size_t)k * 512 + u0 + c4 * 4];
        *(float4*)&Wl[k][c4 * 4] = v;
    }
    __syncthreads();

    const int kb = ks * 128;
    const float* const rowbase = out + (size_t)bb * T_ * U_;

    // Reducer-role mapping (tid < 128): wave b2 handles batch b2, column u0+u.
    const int b2 = tid >> 6;
    const int u = tid & 63;
    float* const hptr = out + (size_t)(2 * g + b2) * T_ * U_ + u0 + u;
    // flag[g][peer j][half] ; reducer wave b2 of block j sets (j,b2).
    unsigned* const myflag  = flags + g * 16 + j * 2 + b2;
    // watcher: wave (ks,b) needs h-slices from peers {2ks, 2ks+1}, half b.
    unsigned* const srcflag = flags + g * 16 + (2 * ks + (lane & 1)) * 2 + b;

    for (int t = 0; t < T_; ++t) {
        // Prefetch xw(t) (stable since kernel A; overwritten only later this iter).
        float xwv = 0.f;
        if (tid < 128) xwv = hptr[(size_t)t * U_];

        if (t > 0) {
            // Wait for h(t-1): the 2 source flags must reach t. Lanes 0-1 poll.
            const unsigned tgt = (unsigned)t;
            bool ok;
            do {
                unsigned v = tgt;
                if (lane < 2)
                    v = __hip_atomic_load(srcflag, __ATOMIC_RELAXED, __HIP_MEMORY_SCOPE_AGENT);
                ok = __all((int)(v >= tgt));
            } while (!ok);
            __builtin_amdgcn_fence(__ATOMIC_ACQUIRE, "agent");

            // Load this wave's h(t-1) chunk (128 floats, coalesced, L2-local).
            const float* hp = rowbase + (size_t)(t - 1) * U_ + kb;
            float hr0 = hp[lane];
            float hr1 = hp[64 + lane];

            // Partial dot over 128 k's: h broadcast via readlane, W from LDS.
            float a0 = 0.f, a1 = 0.f, a2 = 0.f, a3 = 0.f;
#pragma unroll
            for (int q = 0; q < 64; q += 4) {
                a0 += lane_bcast(hr0, q + 0) * Wl[kb + q + 0][lane];
                a1 += lane_bcast(hr0, q + 1) * Wl[kb + q + 1][lane];
                a2 += lane_bcast(hr0, q + 2) * Wl[kb + q + 2][lane];
                a3 += lane_bcast(hr0, q + 3) * Wl[kb + q + 3][lane];
            }
#pragma unroll
            for (int q = 0; q < 64; q += 4) {
                a0 += lane_bcast(hr1, q + 0) * Wl[kb + 64 + q + 0][lane];
                a1 += lane_bcast(hr1, q + 1) * Wl[kb + 64 + q + 1][lane];
                a2 += lane_bcast(hr1, q + 2) * Wl[kb + 64 + q + 2][lane];
                a3 += lane_bcast(hr1, q + 3) * Wl[kb + 64 + q + 3][lane];
            }
            part[t & 1][ks][b][lane] = (a0 + a1) + (a2 + a3);
        }
        __syncthreads();

        // Reducer waves: sum 4 partials, add xw, tanh, store h(t), release flag.
        if (tid < 128) {
            float s = 0.f;
            if (t > 0) {
                const float* pp = &part[t & 1][0][b2][u];
                s = (pp[0] + pp[128]) + (pp[256] + pp[384]);
            }
            hptr[(size_t)t * U_] = tanhf(xwv + s);
            if (lane == 0)  // wave-level vmcnt drain in the release orders all 64 lanes' stores
                __hip_atomic_store(myflag, (unsigned)(t + 1), __ATOMIC_RELEASE,
                                   __HIP_MEMORY_SCOPE_AGENT);
        }
    }
}

extern "C" void kernel_launch(void* const* d_in, const int* in_sizes, int n_in,
                              void* d_out, int out_size, void* d_ws, size_t ws_size,
                              hipStream_t stream) {
    const float* x    = (const float*)d_in[0];
    const float* Win  = (const float*)d_in[1];
    const float* Wrec = (const float*)d_in[2];
    const float* bias = (const float*)d_in[3];
    float* out = (float*)d_out;

    // Zero the flag array (32 groups x 16 words); d_ws is re-poisoned each call.
    hipMemsetAsync(d_ws, 0, 2048, stream);

    dim3 gA(256, 4), bA(256);
    rnn_inproj_gemm<<<gA, bA, 0, stream>>>(x, Win, bias, out);

    unsigned* flags = (unsigned*)d_ws;
    void* args[] = { (void*)&Wrec, (void*)&out, (void*)&flags };
    hipLaunchCooperativeKernel((const void*)rnn_scan, dim3(256), dim3(512), args, 0, stream);
}